// Round 15
// baseline (247.094 us; speedup 1.0000x reference)
//
#include <hip/hip_runtime.h>
#include <math.h>

#define NN 20000   // nodes
#define NE 480000  // edges
#define NB 4       // batch
#define ND 32      // dim
#define NR 474     // relations
#define NL 3       // layers
#define NT 64      // tails
#define M_TOT (NB * NN)   // 80000 node-rows
#define LROW 168          // padded LDS row (bf16 units); 336B stride
#define NTILES 625        // 32-row tiles per batch
#define REL_BYTES (NR * ND * 4)              // 60672
#define AB_BYTES (2 * 32 * LROW * 2)         // 21504 per (hi|lo): 2 groups
#define DYN_LDS (REL_BYTES + 2 * AB_BYTES + 16)   // 103696

typedef __attribute__((ext_vector_type(8))) short bf16x8v;
typedef __attribute__((ext_vector_type(4))) float f32x4v;

// RNE split of f32 into bf16 hi + bf16 lo (a ~= hi + lo, err ~2^-18 rel)
__device__ inline void bf16split(float a, unsigned short& h, unsigned short& l) {
    unsigned u = __float_as_uint(a);
    unsigned r = u + 0x7FFFu + ((u >> 16) & 1u);
    h = (unsigned short)(r >> 16);
    float fh = __uint_as_float((unsigned)h << 16);
    float res = a - fh;
    unsigned v = __float_as_uint(res);
    unsigned r2 = v + 0x7FFFu + ((v >> 16) & 1u);
    l = (unsigned short)(r2 >> 16);
}

// ---------------- CSR build ----------------
__global__ __launch_bounds__(256) void count_kernel(const int* __restrict__ dst,
                                                    int* __restrict__ indeg) {
    int e = blockIdx.x * blockDim.x + threadIdx.x;
    if (e < NE) atomicAdd(&indeg[dst[e]], 1);
}

// parallel per-node prep: wave-scan + ONE atomic per wave for the slab allocator
__global__ __launch_bounds__(256) void nodeprep_kernel(
    const int* __restrict__ indeg, int* __restrict__ offsets,
    int* __restrict__ bucketCnt, float* __restrict__ logsum,
    int* __restrict__ edgeTotal) {
    __shared__ int hcnt[256];
    int t = threadIdx.x;
    hcnt[t] = 0;
    __syncthreads();

    int n = blockIdx.x * 256 + t;
    int lane = t & 63;
    int dg = (n < NN) ? indeg[n] : 0;
    float v = (n < NN) ? logf((float)(dg + 2)) : 0.f;   // log(deg+1), deg = indeg+1

    int inc = dg;
    #pragma unroll
    for (int o = 1; o < 64; o <<= 1) {
        int u = __shfl_up(inc, o, 64);
        if (lane >= o) inc += u;
    }
    int waveTot = __shfl(inc, 63, 64);
    int base = 0;
    if (lane == 63) base = atomicAdd(edgeTotal, waveTot);   // 1 atomic per wave
    base = __shfl(base, 63, 64);
    if (n < NN) {
        offsets[n] = base + inc - dg;
        atomicAdd(&hcnt[dg > 255 ? 255 : dg], 1);           // LDS histogram
    }
    #pragma unroll
    for (int o = 32; o > 0; o >>= 1) v += __shfl_down(v, o, 64);
    if (lane == 0) atomicAdd(logsum, v);
    __syncthreads();
    if (hcnt[t]) atomicAdd(&bucketCnt[t], hcnt[t]);         // spread over 256 addrs
}

// tiny 1-block exclusive prefix over 256 bucket counts -> bucketCursor
__global__ __launch_bounds__(256) void bucket_prefix_kernel(
    const int* __restrict__ bucketCnt, int* __restrict__ bucketCursor) {
    __shared__ int s[256];
    int t = threadIdx.x;
    s[t] = bucketCnt[t];
    __syncthreads();
    for (int off = 1; off < 256; off <<= 1) {
        int v = (t >= off) ? s[t - off] : 0;
        __syncthreads();
        s[t] += v;
        __syncthreads();
    }
    bucketCursor[t] = s[t] - bucketCnt[t];       // exclusive base
}

// parallel per-node: block-level two-phase bucket placement (LDS rank + slab atomic)
__global__ __launch_bounds__(256) void sortmap_kernel(
    const int* __restrict__ indeg, const int* __restrict__ offsets,
    int* __restrict__ bucketCursor, const float* __restrict__ logsum,
    int* __restrict__ ipern, int2* __restrict__ begdeg,
    float2* __restrict__ scales2, int* __restrict__ hpos,
    const int* __restrict__ h_index) {
    __shared__ int hcnt[256];
    __shared__ int hbase[256];
    int t = threadIdx.x;
    hcnt[t] = 0;
    __syncthreads();

    int n = blockIdx.x * 256 + t;
    int dg = 0, bkt = 0, rank = 0;
    if (n < NN) {
        dg = indeg[n];
        bkt = dg > 255 ? 255 : dg;
        rank = atomicAdd(&hcnt[bkt], 1);         // intra-block rank (LDS)
    }
    __syncthreads();
    if (hcnt[t]) hbase[t] = atomicAdd(&bucketCursor[t], hcnt[t]);  // slab per (block,bucket)
    __syncthreads();
    if (n >= NN) return;
    int pos = hbase[bkt] + rank;
    ipern[n] = pos;
    begdeg[pos] = make_int2(offsets[n], dg);
    float fac = (float)NN / *logsum;
    float scl = logf((float)(dg + 2)) * fac;
    scales2[pos] = make_float2(scl, 1.0f / fmaxf(scl, 1e-2f));
    #pragma unroll
    for (int b = 0; b < NB; ++b)
        if (n == h_index[b]) hpos[b] = pos;
}

// csr scatter (BYTE offsets in SORTED space) + boundary-init tail block
#define SCAT_BLKS (NE / 256)   // 1875 exact
__global__ __launch_bounds__(256) void scatter_kernel(const int* __restrict__ src,
                                                      const int* __restrict__ dst,
                                                      const int* __restrict__ etype,
                                                      const int* __restrict__ offsets,
                                                      const int* __restrict__ ipern,
                                                      int* __restrict__ cursor,
                                                      int2* __restrict__ csr,
                                                      float* __restrict__ h0,
                                                      const int* __restrict__ hpos,
                                                      const int* __restrict__ r_index,
                                                      const float* __restrict__ qw) {
    if (blockIdx.x == SCAT_BLKS) {               // boundary init (h0 pre-zeroed)
        int i = threadIdx.x;
        if (i < NB * ND) {
            int b = i >> 5, d = i & 31;
            h0[((size_t)b * NN + hpos[b]) * ND + d] = qw[r_index[b] * ND + d];
        }
        return;
    }
    int e = blockIdx.x * 256 + threadIdx.x;
    int dn = dst[e];
    int pos = atomicAdd(&cursor[dn], 1);
    csr[offsets[dn] + pos] = make_int2(ipern[src[e]] * (ND * 4), etype[e] * (ND * 4));
}

// ---------------- rel embeddings (4 batches/thread) + W pack, one kernel ----------------
#define REL_T (NL * NR * ND)              // 45504
#define REL_BLOCKS ((REL_T + 255) / 256)  // 178
__global__ __launch_bounds__(256) void relwpack_kernel(
    const float* __restrict__ qw, const int* __restrict__ r_index,
    const float* __restrict__ rlw, float* __restrict__ rel,
    const float* __restrict__ W, unsigned short* __restrict__ Wph,
    unsigned short* __restrict__ Wpl) {
    if (blockIdx.x < REL_BLOCKS) {
        int i = blockIdx.x * 256 + threadIdx.x;
        if (i >= REL_T) return;
        int d = i & (ND - 1);
        int rd = i >> 5;
        int r = rd % NR;
        int l = rd / NR;
        const float* q0 = qw + r_index[0] * ND;
        const float* q1 = qw + r_index[1] * ND;
        const float* q2 = qw + r_index[2] * ND;
        const float* q3 = qw + r_index[3] * ND;
        const float* w = rlw + (size_t)l * ND * NR * ND + (size_t)r * ND + d;
        float a0 = 0.f, a1 = 0.f, a2 = 0.f, a3 = 0.f;
        #pragma unroll
        for (int k = 0; k < ND; ++k) {
            float wk = w[(size_t)k * NR * ND];
            a0 = fmaf(q0[k], wk, a0); a1 = fmaf(q1[k], wk, a1);
            a2 = fmaf(q2[k], wk, a2); a3 = fmaf(q3[k], wk, a3);
        }
        size_t o = ((size_t)l * NB * NR + r) * ND + d;
        rel[o] = a0;
        rel[o + (size_t)NR * ND] = a1;
        rel[o + (size_t)2 * NR * ND] = a2;
        rel[o + (size_t)3 * NR * ND] = a3;
    } else {
        int t = (blockIdx.x - REL_BLOCKS) * 256 + threadIdx.x;
        if (t >= NL * 2 * 13 * 64) return;
        int lane = t & 63;
        int u = t >> 6;
        int s = u % 13;
        int nt = (u / 13) % 2;
        int l = u / 26;
        int n = nt * 16 + (lane & 15);
        int k0 = s * 32 + (lane >> 4) * 8;
        size_t ob = (size_t)t * 8;
        #pragma unroll
        for (int e = 0; e < 8; ++e) {
            float w = W[(size_t)l * 416 * 32 + (size_t)(k0 + e) * 32 + n];
            unsigned short h8, l8;
            bf16split(w, h8, l8);
            Wph[ob + e] = h8;
            Wpl[ob + e] = l8;
        }
    }
}

// ---------------- persistent fused layer: rel-in-LDS + work-stolen tiles ----------------
// 256 blocks x 512 threads = 2 groups of (4 waves, 32 rows). Block's batch = blockIdx&3
// (XCD round-robin heuristic -> batch-local L2). rel table (60.7KB f32) staged in LDS
// once per block: kills the rel half of all scattered gather lines (the R8-R14 ~48us
// invariant = line-throughput bound). Tiles stolen 2-at-a-time via per-(layer,batch)
// atomic cursor -> no drain tail. Dynamic LDS 103.7KB (1 block/CU, 8 waves).
__global__ __launch_bounds__(512, 2) void layer_fused_kernel(
    const float* __restrict__ hin, float* __restrict__ hnew,
    const float* __restrict__ relG,              // [B][R][D] this layer
    const unsigned short* __restrict__ Wph, const unsigned short* __restrict__ Wpl,
    const float* __restrict__ bias, const float2* __restrict__ scales2,
    const int2* __restrict__ begdeg, const int2* __restrict__ csr,
    const int* __restrict__ hpos, const int* __restrict__ r_index,
    const float* __restrict__ qw, int* __restrict__ tileCursor) {
    extern __shared__ __align__(16) char smem[];
    float* ldsRel = (float*)smem;                                    // 60672 B
    unsigned short* AhBase = (unsigned short*)(smem + REL_BYTES);    // [2][32][LROW]
    unsigned short* AlBase = (unsigned short*)(smem + REL_BYTES + AB_BYTES);
    int* stealSlot = (int*)(smem + REL_BYTES + 2 * AB_BYTES);

    int tid = threadIdx.x;
    int b = blockIdx.x & 3;                      // batch affinity (64 blocks/batch)
    // stage this batch's rel table into LDS (once; ~10-tile amortization)
    {
        const float4* rg = (const float4*)(relG + (size_t)b * NR * ND);
        float4* rl = (float4*)ldsRel;
        for (int i = tid; i < NR * ND / 4; i += 512) rl[i] = rg[i];
    }

    int g = tid >> 8;                            // group 0/1
    int t256 = tid & 255;
    int lane = t256 & 63;
    int w4 = t256 >> 6;                          // wave within group: 0..3
    int r8 = lane >> 3;
    int d0 = (lane & 7) * 4;                     // dim quartet
    int d4 = d0 * 4;                             // byte offset
    int rowl = w4 * 8 + r8;                      // 0..31 within tile
    const char* hbB = (const char*)hin + (size_t)b * (NN * ND * 4) + d4;
    const char* reL = (const char*)ldsRel + d4;
    unsigned short* ldsAh = AhBase + g * 32 * LROW;
    unsigned short* ldsAl = AlBase + g * 32 * LROW;
    int hp = hpos[b];

    for (;;) {
        __syncthreads();                         // protect A-bufs & stealSlot
        if (tid == 0) *stealSlot = atomicAdd(&tileCursor[b], 2);
        __syncthreads();
        int t0 = *stealSlot;
        if (t0 >= NTILES) break;                 // block-uniform exit
        int myt = t0 + g;
        bool active = (myt < NTILES);

        int sidx = 0, dg = 0;
        if (active) {
            sidx = myt * 32 + rowl;              // sorted-space row (this batch)
            float sv[4], ssv[4], mxv[4], mnv[4];
            {
                float4 bm4 = make_float4(0.f, 0.f, 0.f, 0.f);
                if (sidx == hp) bm4 = *(const float4*)(qw + r_index[b] * ND + d0);
                float bm[4] = {bm4.x, bm4.y, bm4.z, bm4.w};
                #pragma unroll
                for (int c = 0; c < 4; ++c) {
                    sv[c] = bm[c]; ssv[c] = bm[c] * bm[c]; mxv[c] = bm[c]; mnv[c] = bm[c];
                }
            }
            int2 bd = begdeg[sidx];
            int beg = bd.x; dg = bd.y;
            int end = beg + dg;
#define EDGE1(E)                                                                  \
    {                                                                             \
        int2 a0 = csr[E];                                                         \
        float4 h0 = *(const float4*)(hbB + a0.x);                                 \
        float4 r0 = *(const float4*)(reL + a0.y);                                 \
        float m0[4] = {h0.x * r0.x, h0.y * r0.y, h0.z * r0.z, h0.w * r0.w};       \
        _Pragma("unroll")                                                         \
        for (int c = 0; c < 4; ++c) {                                             \
            sv[c] += m0[c];                                                       \
            ssv[c] = fmaf(m0[c], m0[c], ssv[c]);                                  \
            mxv[c] = fmaxf(mxv[c], m0[c]);                                        \
            mnv[c] = fminf(mnv[c], m0[c]);                                        \
        }                                                                         \
    }
            int e = beg;
            if ((e & 1) && e < end) { EDGE1(e); ++e; }   // 16B-align for int4
            int n8 = (end - e) >> 3;
            const int4* cp = (const int4*)(csr + e);
            e += n8 * 8;
            int4 k0, k1, k2, k3;
            if (n8 > 0) { k0 = cp[0]; k1 = cp[1]; k2 = cp[2]; k3 = cp[3]; }
            for (int i = 0; i < n8; ++i) {
                float4 h0 = *(const float4*)(hbB + k0.x), r0 = *(const float4*)(reL + k0.y);
                float4 h1 = *(const float4*)(hbB + k0.z), r1 = *(const float4*)(reL + k0.w);
                float4 h2 = *(const float4*)(hbB + k1.x), r2 = *(const float4*)(reL + k1.y);
                float4 h3 = *(const float4*)(hbB + k1.z), r3 = *(const float4*)(reL + k1.w);
                float4 h4 = *(const float4*)(hbB + k2.x), r4 = *(const float4*)(reL + k2.y);
                float4 h5 = *(const float4*)(hbB + k2.z), r5 = *(const float4*)(reL + k2.w);
                float4 h6 = *(const float4*)(hbB + k3.x), r6 = *(const float4*)(reL + k3.y);
                float4 h7 = *(const float4*)(hbB + k3.z), r7 = *(const float4*)(reL + k3.w);
                cp += 4;
                if (i + 1 < n8) { k0 = cp[0]; k1 = cp[1]; k2 = cp[2]; k3 = cp[3]; }
                float m0[4] = {h0.x * r0.x, h0.y * r0.y, h0.z * r0.z, h0.w * r0.w};
                float m1[4] = {h1.x * r1.x, h1.y * r1.y, h1.z * r1.z, h1.w * r1.w};
                float m2[4] = {h2.x * r2.x, h2.y * r2.y, h2.z * r2.z, h2.w * r2.w};
                float m3[4] = {h3.x * r3.x, h3.y * r3.y, h3.z * r3.z, h3.w * r3.w};
                float m4[4] = {h4.x * r4.x, h4.y * r4.y, h4.z * r4.z, h4.w * r4.w};
                float m5[4] = {h5.x * r5.x, h5.y * r5.y, h5.z * r5.z, h5.w * r5.w};
                float m6[4] = {h6.x * r6.x, h6.y * r6.y, h6.z * r6.z, h6.w * r6.w};
                float m7[4] = {h7.x * r7.x, h7.y * r7.y, h7.z * r7.z, h7.w * r7.w};
                #pragma unroll
                for (int c = 0; c < 4; ++c) {
                    sv[c] += ((m0[c] + m1[c]) + (m2[c] + m3[c])) +
                             ((m4[c] + m5[c]) + (m6[c] + m7[c]));
                    ssv[c] = fmaf(m0[c], m0[c], ssv[c]);
                    ssv[c] = fmaf(m1[c], m1[c], ssv[c]);
                    ssv[c] = fmaf(m2[c], m2[c], ssv[c]);
                    ssv[c] = fmaf(m3[c], m3[c], ssv[c]);
                    ssv[c] = fmaf(m4[c], m4[c], ssv[c]);
                    ssv[c] = fmaf(m5[c], m5[c], ssv[c]);
                    ssv[c] = fmaf(m6[c], m6[c], ssv[c]);
                    ssv[c] = fmaf(m7[c], m7[c], ssv[c]);
                    mxv[c] = fmaxf(fmaxf(mxv[c], m0[c]), m1[c]);
                    mxv[c] = fmaxf(fmaxf(mxv[c], m2[c]), m3[c]);
                    mxv[c] = fmaxf(fmaxf(mxv[c], m4[c]), m5[c]);
                    mxv[c] = fmaxf(fmaxf(mxv[c], m6[c]), m7[c]);
                    mnv[c] = fminf(fminf(mnv[c], m0[c]), m1[c]);
                    mnv[c] = fminf(fminf(mnv[c], m2[c]), m3[c]);
                    mnv[c] = fminf(fminf(mnv[c], m4[c]), m5[c]);
                    mnv[c] = fminf(fminf(mnv[c], m6[c]), m7[c]);
                }
            }
            for (; e < end; ++e) EDGE1(e);
#undef EDGE1
            float degf = (float)(dg + 1);
            float inv = 1.0f / degf;
            float4 h4s = *(const float4*)(hbB + sidx * (ND * 4));
            float hself[4] = {h4s.x, h4s.y, h4s.z, h4s.w};
            #pragma unroll
            for (int f = 0; f < 5; ++f) {
                float vals[4];
                #pragma unroll
                for (int c = 0; c < 4; ++c) {
                    float v;
                    if (f == 0) v = hself[c];
                    else if (f == 1) v = sv[c] * inv;
                    else if (f == 2) v = mxv[c];
                    else if (f == 3) v = mnv[c];
                    else {
                        float mean = sv[c] * inv;
                        v = sqrtf(fmaxf(ssv[c] * inv - mean * mean, 0.f));
                    }
                    vals[c] = v;
                }
                ushort4 vh, vl;
                bf16split(vals[0], vh.x, vl.x);
                bf16split(vals[1], vh.y, vl.y);
                bf16split(vals[2], vh.z, vl.z);
                bf16split(vals[3], vh.w, vl.w);
                *(ushort4*)&ldsAh[rowl * LROW + f * 32 + d0] = vh;
                *(ushort4*)&ldsAl[rowl * LROW + f * 32 + d0] = vl;
            }
        }
        __syncthreads();
        if (!active) continue;

        // -------- phase 2: MFMA update --------
        int mt = w4 >> 1, nt = w4 & 1;
        int am = lane & 15, kg = lane >> 4;
        int arow = mt * 16 + am;
        const bf16x8v* Bh = (const bf16x8v*)(Wph + (size_t)nt * 13 * 64 * 8);
        const bf16x8v* Bl = (const bf16x8v*)(Wpl + (size_t)nt * 13 * 64 * 8);

        f32x4v acc_a = {0.f, 0.f, 0.f, 0.f};
        f32x4v acc2  = {0.f, 0.f, 0.f, 0.f};
        f32x4v acc3  = {0.f, 0.f, 0.f, 0.f};
#define STEP(S, ACC)                                                              \
    {                                                                             \
        bf16x8v bh = Bh[(S) * 64 + lane];                                         \
        bf16x8v bl = Bl[(S) * 64 + lane];                                         \
        ACC = __builtin_amdgcn_mfma_f32_16x16x32_bf16(ah, bh, ACC, 0, 0, 0);      \
        ACC = __builtin_amdgcn_mfma_f32_16x16x32_bf16(ah, bl, ACC, 0, 0, 0);      \
        ACC = __builtin_amdgcn_mfma_f32_16x16x32_bf16(al, bh, ACC, 0, 0, 0);      \
    }
        #pragma unroll
        for (int c = 0; c < 5; ++c) {
            bf16x8v ah = *(const bf16x8v*)&ldsAh[arow * LROW + c * 32 + kg * 8];
            bf16x8v al = *(const bf16x8v*)&ldsAl[arow * LROW + c * 32 + kg * 8];
            if (c == 0) {
                STEP(0, acc_a)
            } else {
                STEP(c, acc_a)
                STEP(c + 4, acc2)
                STEP(c + 8, acc3)
            }
        }
#undef STEP
        int j = nt * 16 + am;
        float bj = bias[j];
        #pragma unroll
        for (int rr = 0; rr < 4; ++rr) {
            int srow = myt * 32 + mt * 16 + 4 * kg + rr;    // sorted row in batch b
            float2 sc = scales2[srow];
            float v = acc_a[rr] + sc.x * acc2[rr] + sc.y * acc3[rr] + bj;
            size_t o = ((size_t)b * NN + srow) * 32 + j;
            hnew[o] = fmaxf(v, 0.f) + hin[o];
        }
    }
}

// ---------------- final MLP scorer: block per (b,t), lane per hidden unit ----------------
__global__ __launch_bounds__(64) void score_kernel(
    const float* __restrict__ hidden, const int* __restrict__ t_index,
    const int* __restrict__ ipern,
    const int* __restrict__ r_index, const float* __restrict__ qw,
    const float* __restrict__ w1, const float* __restrict__ b1,
    const float* __restrict__ w2, const float* __restrict__ b2,
    float* __restrict__ out) {
    int i = blockIdx.x;                       // 0..NB*NT-1
    int b = i / NT;
    int j = threadIdx.x;                      // 0..63
    int node = ipern[t_index[i]];             // sorted-space row
    __shared__ float feat[2 * ND];
    if (j < ND) feat[j] = hidden[((size_t)b * NN + node) * ND + j];
    else feat[j] = qw[r_index[b] * ND + (j - ND)];
    __syncthreads();
    float a = b1[j];
    #pragma unroll
    for (int kk = 0; kk < 2 * ND; ++kk) a = fmaf(feat[kk], w1[kk * 2 * ND + j], a);
    float v = fmaxf(a, 0.f) * w2[j];
    #pragma unroll
    for (int off = 32; off > 0; off >>= 1) v += __shfl_down(v, off, 64);
    if (j == 0) out[i] = v + b2[0];
}

extern "C" void kernel_launch(void* const* d_in, const int* in_sizes, int n_in,
                              void* d_out, int out_size, void* d_ws, size_t ws_size,
                              hipStream_t stream) {
    (void)in_sizes; (void)n_in; (void)out_size; (void)ws_size;
    const int* edge_index = (const int*)d_in[0];     // [2][E]
    const int* edge_type  = (const int*)d_in[1];     // [E]
    const int* h_index    = (const int*)d_in[2];     // [B]
    const int* r_index    = (const int*)d_in[3];     // [B]
    const int* t_index    = (const int*)d_in[4];     // [B][T]
    const float* query_weight = (const float*)d_in[5];  // [R][D]
    const float* rel_lin_w    = (const float*)d_in[6];  // [L][D][R*D]
    const float* layer_w      = (const float*)d_in[7];  // [L][13D][D]
    const float* layer_b      = (const float*)d_in[8];  // [L][D]
    const float* mlp_w1 = (const float*)d_in[9];
    const float* mlp_b1 = (const float*)d_in[10];
    const float* mlp_w2 = (const float*)d_in[11];
    const float* mlp_b2 = (const float*)d_in[12];
    float* out = (float*)d_out;

    const int* src = edge_index;
    const int* dst = edge_index + NE;

    char* wsp = (char*)d_ws;
    size_t off = 0;
    auto alloc = [&](size_t bytes) -> void* {
        void* p = wsp + off;
        off += (bytes + 255) & ~(size_t)255;
        return p;
    };
    float* h0      = (float*)alloc(sizeof(float) * M_TOT * ND);
    float* h1      = (float*)alloc(sizeof(float) * M_TOT * ND);
    unsigned short* Wph = (unsigned short*)alloc(sizeof(unsigned short) * NL * 2 * 13 * 64 * 8);
    unsigned short* Wpl = (unsigned short*)alloc(sizeof(unsigned short) * NL * 2 * 13 * 64 * 8);
    float* rel     = (float*)alloc(sizeof(float) * NL * NB * NR * ND);
    int2*  csr     = (int2*)alloc(sizeof(int2) * NE);
    int*   offsets = (int*)alloc(sizeof(int) * NN);
    int*   ic      = (int*)alloc(sizeof(int) * 2 * NN);   // indeg | cursor (one memset)
    int*   indeg   = ic;
    int*   cursor  = ic + NN;
    int*   ipern   = (int*)alloc(sizeof(int) * NN);
    int2*  begdeg  = (int2*)alloc(sizeof(int2) * NN);
    float2* scales2 = (float2*)alloc(sizeof(float2) * NN);
    int*   hpos    = (int*)alloc(sizeof(int) * NB);
    int*   bucketCnt    = (int*)alloc(sizeof(int) * 256);
    int*   bucketCursor = (int*)alloc(sizeof(int) * 256);
    float* logsum  = (float*)alloc(sizeof(float) * 1);
    int*   edgeTotal = (int*)alloc(sizeof(int) * 1);
    int*   tileCursor = (int*)alloc(sizeof(int) * 4 * NL);   // per (layer, batch)
    size_t zbytes = (size_t)((char*)(tileCursor + 4 * NL) - (char*)bucketCnt);

    hipMemsetAsync(ic, 0, sizeof(int) * 2 * NN, stream);
    hipMemsetAsync(bucketCnt, 0, zbytes, stream);
    hipMemsetAsync(h0, 0, sizeof(float) * M_TOT * ND, stream);

    count_kernel<<<(NE + 255) / 256, 256, 0, stream>>>(dst, indeg);
    nodeprep_kernel<<<(NN + 255) / 256, 256, 0, stream>>>(indeg, offsets, bucketCnt,
                                                          logsum, edgeTotal);
    bucket_prefix_kernel<<<1, 256, 0, stream>>>(bucketCnt, bucketCursor);
    sortmap_kernel<<<(NN + 255) / 256, 256, 0, stream>>>(indeg, offsets, bucketCursor,
                                                         logsum, ipern, begdeg, scales2,
                                                         hpos, h_index);
    scatter_kernel<<<SCAT_BLKS + 1, 256, 0, stream>>>(src, dst, edge_type, offsets,
                                                      ipern, cursor, csr,
                                                      h0, hpos, r_index, query_weight);
    relwpack_kernel<<<REL_BLOCKS + (NL * 2 * 13 * 64 + 255) / 256, 256, 0, stream>>>(
        query_weight, r_index, rel_lin_w, rel, layer_w, Wph, Wpl);

    static bool attr_set = false;
    if (!attr_set) {
        hipFuncSetAttribute((const void*)layer_fused_kernel,
                            hipFuncAttributeMaxDynamicSharedMemorySize, 160 * 1024);
        attr_set = true;
    }

    float* hin = h0;
    float* hout = h1;
    for (int l = 0; l < NL; ++l) {
        layer_fused_kernel<<<256, 512, DYN_LDS, stream>>>(
            hin, hout, rel + (size_t)l * NB * NR * ND,
            Wph + (size_t)l * 2 * 13 * 64 * 8, Wpl + (size_t)l * 2 * 13 * 64 * 8,
            layer_b + (size_t)l * ND, scales2,
            begdeg, csr, hpos, r_index, query_weight, tileCursor + 4 * l);
        float* t = hin; hin = hout; hout = t;
    }
    // final hidden is in `hin`

    score_kernel<<<NB * NT, 64, 0, stream>>>(hin, t_index, ipern, r_index, query_weight,
                                             mlp_w1, mlp_b1, mlp_w2, mlp_b2, out);
}